// Round 4
// baseline (2508.660 us; speedup 1.0000x reference)
//
#include <hip/hip_runtime.h>

#define SUB   8
#define INCH  64
#define IMH   128
#define IMW   128
#define OUTCH 128
#define OH    126
#define OW    126

#define SLOTS 6
#define NCH   39              // 32 owned + 7 halo channels
#define CHW   40              // words per (slot,ch) row: 36 used + 4 pad (bank spread)
#define SLOTW (NCH * CHW)     // 1560 words
#define LDSW  (SLOTS * SLOTW) // 9360 words = 37440 B -> 4 blocks/CU

// ---- weight prep: chunk c = s*64 + o0 (o0 in [0,64)): 20 floats, 16B aligned
//      t0..8 = W[o0][s][.][.],  t9..17 = W[o0+64][s][.][.]
__global__ __launch_bounds__(256)
void prep_weights_kernel(const float* __restrict__ Wg, float* __restrict__ Wp) {
    int idx = blockIdx.x * 256 + threadIdx.x;
    if (idx < 512 * 18) {
        int chunk = idx / 18;
        int t     = idx - chunk * 18;
        int s = chunk >> 6;
        int p = chunk & 63;
        int o  = (t < 9) ? p : p + 64;
        int tt = (t < 9) ? t : t - 9;
        Wp[chunk * 20 + t] = Wg[(o * SUB + s) * 9 + tt];
    }
}

__global__ __launch_bounds__(256, 4)
void Group_Conv_84731114815961_kernel(const float* __restrict__ X,
                                      const float* __restrict__ Wg,
                                      const float* __restrict__ Bias,
                                      const float* __restrict__ Wp,
                                      float* __restrict__ Out) {
    __shared__ float xin[LDSW];

    const int tx = blockIdx.x & 3;   // x strip (32 cols)
    const int h  = blockIdx.x >> 2;  // channel half
    const int ty = blockIdx.y;       // y strip (16 rows; last 14)
    const int b  = blockIdx.z;
    const int x0 = tx * 32;
    const int y0 = ty * 16;
    const int tid = threadIdx.x;
    const int niter = (ty < 7) ? 8 : 7;

    const float* Xb = X + (size_t)b * INCH * IMH * IMW;

    const int p  = tid >> 3;   // o-pair within half, 0..31
    const int xg = tid & 7;    // 4-col group, 0..7
    const int cb = xg << 2;
    const int o0 = h * 32 + p; // och pair {o0, o0+64}

    // staging granules: 351 float4 per row; thread covers g0 (always), g1 (tid<95)
    const int g0 = tid;
    const int g1 = 256 + tid;
    const bool a1 = (tid < 95);
    const int c0 = g0 / 9, v0 = g0 - c0 * 9;
    const int c1 = g1 / 9, v1 = g1 - c1 * 9;
    int sc0 = x0 + 4 * v0; if (sc0 > IMW - 4) sc0 = IMW - 4;
    int sc1 = x0 + 4 * v1; if (sc1 > IMW - 4) sc1 = IMW - 4;
    const int cg0 = (h * 32 + c0) & 63;
    const int cg1 = (h * 32 + c1) & 63;
    const size_t gs0 = (size_t)cg0 * IMH * IMW + sc0;
    const size_t gs1 = (size_t)cg1 * IMH * IMW + sc1;
    const int ld0 = c0 * CHW + 4 * v0;
    const int ld1 = c1 * CHW + 4 * v1;

    // ---- initial stage: input rows y0..y0+3 ----
    #pragma unroll
    for (int r = 0; r < 4; ++r) {
        const int ri = y0 + r;
        const int sl = ri % 6;
        const float4 va = *reinterpret_cast<const float4*>(Xb + gs0 + (size_t)ri * IMW);
        *reinterpret_cast<float4*>(&xin[sl * SLOTW + ld0]) = va;
        if (a1) {
            const float4 vb = *reinterpret_cast<const float4*>(Xb + gs1 + (size_t)ri * IMW);
            *reinterpret_cast<float4*>(&xin[sl * SLOTW + ld1]) = vb;
        }
    }
    __syncthreads();

    const float bz0 = Bias[o0];
    const float bz1 = Bias[o0 + 64];
    const bool useWp = (Wp != nullptr);

    int s0 = y0 % 6;   // ring slot of current base row
    for (int t = 0; t < niter; ++t) {
        const int rbase = y0 + 2 * t;     // out rows rbase, rbase+1
        const bool pre = (t < niter - 1);

        // T14: issue next-2-rows global loads before compute
        float4 fa0, fb0, fa1, fb1;
        if (pre) {
            const size_t r4 = (size_t)(rbase + 4) * IMW;
            const size_t r5 = (size_t)(rbase + 5) * IMW;
            fa0 = *reinterpret_cast<const float4*>(Xb + gs0 + r4);
            fb0 = *reinterpret_cast<const float4*>(Xb + gs0 + r5);
            if (a1) {
                fa1 = *reinterpret_cast<const float4*>(Xb + gs1 + r4);
                fb1 = *reinterpret_cast<const float4*>(Xb + gs1 + r5);
            }
        }

        int sl1 = s0 + 1; if (sl1 >= 6) sl1 -= 6;
        int sl2 = s0 + 2; if (sl2 >= 6) sl2 -= 6;
        int sl3 = s0 + 3; if (sl3 >= 6) sl3 -= 6;
        const int rb[4] = {s0 * SLOTW, sl1 * SLOTW, sl2 * SLOTW, sl3 * SLOTW};

        float acc0[2][4], acc1[2][4];
        #pragma unroll
        for (int y = 0; y < 2; ++y)
            #pragma unroll
            for (int q = 0; q < 4; ++q) { acc0[y][q] = 0.f; acc1[y][q] = 0.f; }

        #pragma unroll
        for (int s = 0; s < SUB; ++s) {
            const int cw = (p + s) * CHW + cb;
            float w0[9], w1[9];
            if (useWp) {
                const float4* wc = reinterpret_cast<const float4*>(Wp + ((s << 6) + o0) * 20);
                const float4 f0 = wc[0], f1 = wc[1], f2 = wc[2], f3 = wc[3], f4 = wc[4];
                w0[0]=f0.x; w0[1]=f0.y; w0[2]=f0.z; w0[3]=f0.w;
                w0[4]=f1.x; w0[5]=f1.y; w0[6]=f1.z; w0[7]=f1.w; w0[8]=f2.x;
                w1[0]=f2.y; w1[1]=f2.z; w1[2]=f2.w;
                w1[3]=f3.x; w1[4]=f3.y; w1[5]=f3.z; w1[6]=f3.w; w1[7]=f4.x; w1[8]=f4.y;
            } else {
                const float* w0p = Wg + (o0 * SUB + s) * 9;
                const float* w1p = Wg + ((o0 + 64) * SUB + s) * 9;
                #pragma unroll
                for (int u = 0; u < 9; ++u) { w0[u] = w0p[u]; w1[u] = w1p[u]; }
            }

            #pragma unroll
            for (int r = 0; r < 4; ++r) {
                const float* ba = &xin[rb[r] + cw];
                const float4 a  = *reinterpret_cast<const float4*>(ba);
                const float2 b2 = *reinterpret_cast<const float2*>(ba + 4);
                const float v[6] = {a.x, a.y, a.z, a.w, b2.x, b2.y};
                #pragma unroll
                for (int i = 0; i < 3; ++i) {
                    const int y = r - i;
                    if (y >= 0 && y < 2) {
                        #pragma unroll
                        for (int j = 0; j < 3; ++j) {
                            const float ww0 = w0[i * 3 + j];
                            const float ww1 = w1[i * 3 + j];
                            #pragma unroll
                            for (int q = 0; q < 4; ++q) {
                                acc0[y][q] = fmaf(v[q + j], ww0, acc0[y][q]);
                                acc1[y][q] = fmaf(v[q + j], ww1, acc1[y][q]);
                            }
                        }
                    }
                }
            }
        }

        // ---- stores: out rows rbase, rbase+1 (always < 126) ----
        const int ox = x0 + cb;
        float* obase = Out + ((size_t)b * OUTCH + o0) * (OH * OW) + (size_t)rbase * OW + ox;
        float* o0r0 = obase;
        float* o0r1 = obase + OW;
        float* o1r0 = obase + (size_t)64 * OH * OW;
        float* o1r1 = o1r0 + OW;
        if (ox + 3 < OW) {
            *reinterpret_cast<float4*>(o0r0) = make_float4(acc0[0][0]+bz0, acc0[0][1]+bz0, acc0[0][2]+bz0, acc0[0][3]+bz0);
            *reinterpret_cast<float4*>(o0r1) = make_float4(acc0[1][0]+bz0, acc0[1][1]+bz0, acc0[1][2]+bz0, acc0[1][3]+bz0);
            *reinterpret_cast<float4*>(o1r0) = make_float4(acc1[0][0]+bz1, acc1[0][1]+bz1, acc1[0][2]+bz1, acc1[0][3]+bz1);
            *reinterpret_cast<float4*>(o1r1) = make_float4(acc1[1][0]+bz1, acc1[1][1]+bz1, acc1[1][2]+bz1, acc1[1][3]+bz1);
        } else {  // ox == 124: cols 124,125 only
            o0r0[0] = acc0[0][0]+bz0; o0r0[1] = acc0[0][1]+bz0;
            o0r1[0] = acc0[1][0]+bz0; o0r1[1] = acc0[1][1]+bz0;
            o1r0[0] = acc1[0][0]+bz1; o1r0[1] = acc1[0][1]+bz1;
            o1r1[0] = acc1[1][0]+bz1; o1r1[1] = acc1[1][1]+bz1;
        }

        // T14: commit prefetched rows to ring slots s0+4, s0+5 (not read this iter)
        if (pre) {
            int sl4 = s0 + 4; if (sl4 >= 6) sl4 -= 6;
            int sl5 = s0 + 5; if (sl5 >= 6) sl5 -= 6;
            *reinterpret_cast<float4*>(&xin[sl4 * SLOTW + ld0]) = fa0;
            *reinterpret_cast<float4*>(&xin[sl5 * SLOTW + ld0]) = fb0;
            if (a1) {
                *reinterpret_cast<float4*>(&xin[sl4 * SLOTW + ld1]) = fa1;
                *reinterpret_cast<float4*>(&xin[sl5 * SLOTW + ld1]) = fb1;
            }
        }
        __syncthreads();
        s0 += 2; if (s0 >= 6) s0 -= 6;
    }
}

extern "C" void kernel_launch(void* const* d_in, const int* in_sizes, int n_in,
                              void* d_out, int out_size, void* d_ws, size_t ws_size,
                              hipStream_t stream) {
    const float* X    = (const float*)d_in[0];
    const float* Wg   = (const float*)d_in[1];
    const float* Bias = (const float*)d_in[2];
    float*       Out  = (float*)d_out;

    float* Wp = nullptr;
    if (d_ws && ws_size >= 512 * 20 * sizeof(float)) {
        Wp = (float*)d_ws;
        prep_weights_kernel<<<36, 256, 0, stream>>>(Wg, Wp);
    }

    // (tx,h) in x, ty in y, b in z: 1024 blocks = 4/CU, whole grid resident
    dim3 grid(8, 8, 16);
    Group_Conv_84731114815961_kernel<<<grid, 256, 0, stream>>>(X, Wg, Bias, Wp, Out);
}

// Round 5
// 240.320 us; speedup vs baseline: 10.4388x; 10.4388x over previous
//
#include <hip/hip_runtime.h>

#define SUB   8
#define INCH  64
#define IMH   128
#define IMW   128
#define OUTCH 128
#define OH    126
#define OW    126

// spatial tile per block (identical to round-1)
#define YT 8
#define XT 16
#define TR (YT + 2)        // 10 input rows
#define RS 20              // LDS row stride (floats); 18 used + 2 pad
#define CHS (TR * RS)      // 200 floats per channel
#define LDSW  (INCH * CHS)   // 12800 words = 51200 B
#define LDSV4 (LDSW / 4)     // 3200 float4

// ---- weight prep: chunk c = s*64 + o0 (o0 in [0,64)): 20 floats, 16B aligned
//      t0..8 = W[o0][s][.][.],  t9..17 = W[o0+64][s][.][.]
__global__ __launch_bounds__(256)
void prep_weights_kernel(const float* __restrict__ Wg, float* __restrict__ Wp) {
    int idx = blockIdx.x * 256 + threadIdx.x;
    if (idx < 512 * 18) {
        int chunk = idx / 18;
        int t     = idx - chunk * 18;
        int s = chunk >> 6;
        int p = chunk & 63;
        int o  = (t < 9) ? p : p + 64;
        int tt = (t < 9) ? t : t - 9;
        Wp[chunk * 20 + t] = Wg[(o * SUB + s) * 9 + tt];
    }
}

// 512 threads over the round-1 tile: thread = (o-pair p 0..63) x (y-half) x (4-col group)
__global__ __launch_bounds__(512, 6)
void Group_Conv_84731114815961_kernel(const float* __restrict__ X,
                                      const float* __restrict__ Wg,
                                      const float* __restrict__ Bias,
                                      const float* __restrict__ Wp,
                                      float* __restrict__ Out) {
    __shared__ float xin[LDSW];   // 51200 B -> 3 blocks/CU, 24 waves/CU

    const int tx  = blockIdx.x;   // 0..7   (fastest in dispatch — round-1 order)
    const int ty  = blockIdx.y;   // 0..15
    const int b   = blockIdx.z;   // 0..15
    const int x0  = tx * XT;
    const int y0  = ty * YT;
    const int tid = threadIdx.x;

    // ---- stage input tile: 64 ch x 10 rows x 18 cols (stride 20), R1 pattern ----
    const float* Xb = X + (size_t)b * INCH * IMH * IMW;
    #pragma unroll
    for (int it = 0; it < 7; ++it) {
        int k = it * 512 + tid;
        if (k < LDSV4) {
            int fi  = k * 4;
            int c   = fi / CHS;
            int rem = fi - c * CHS;
            int r   = rem / RS;
            int col = rem - r * RS;          // 0,4,8,12,16
            int sr = y0 + r;   if (sr > IMH - 1) sr = IMH - 1;
            int sc = x0 + col; if (sc > IMW - 4) sc = IMW - 4;
            const float4 v = *reinterpret_cast<const float4*>(Xb + (c * IMH + sr) * IMW + sc);
            *reinterpret_cast<float4*>(&xin[fi]) = v;
        }
    }
    __syncthreads();

    const int p  = tid >> 3;          // o-pair 0..63  (o = p, p+64)
    const int yh = (tid >> 2) & 1;    // y half: rows 4*yh .. 4*yh+3
    const int xg = tid & 3;           // 4-col group
    const int cb = xg << 2;

    float acc0[4][4];
    float acc1[4][4];
    #pragma unroll
    for (int y = 0; y < 4; ++y)
        #pragma unroll
        for (int q = 0; q < 4; ++q) { acc0[y][q] = 0.f; acc1[y][q] = 0.f; }

    const bool useWp = (Wp != nullptr);

    for (int s = 0; s < SUB; ++s) {
        const int c = (p + s) & 63;
        float w0[9], w1[9];
        if (useWp) {
            const float4* wc = reinterpret_cast<const float4*>(Wp + ((s << 6) + p) * 20);
            const float4 f0 = wc[0], f1 = wc[1], f2 = wc[2], f3 = wc[3], f4 = wc[4];
            w0[0]=f0.x; w0[1]=f0.y; w0[2]=f0.z; w0[3]=f0.w;
            w0[4]=f1.x; w0[5]=f1.y; w0[6]=f1.z; w0[7]=f1.w; w0[8]=f2.x;
            w1[0]=f2.y; w1[1]=f2.z; w1[2]=f2.w;
            w1[3]=f3.x; w1[4]=f3.y; w1[5]=f3.z; w1[6]=f3.w; w1[7]=f4.x; w1[8]=f4.y;
        } else {
            const float* w0p = Wg + (p * SUB + s) * 9;
            const float* w1p = Wg + ((p + 64) * SUB + s) * 9;
            #pragma unroll
            for (int t = 0; t < 9; ++t) { w0[t] = w0p[t]; w1[t] = w1p[t]; }
        }

        const float* base = &xin[c * CHS + (yh << 2) * RS + cb];
        #pragma unroll
        for (int r = 0; r < 6; ++r) {
            const float4 a  = *reinterpret_cast<const float4*>(base + r * RS);
            const float2 b2 = *reinterpret_cast<const float2*>(base + r * RS + 4);
            const float v[6] = {a.x, a.y, a.z, a.w, b2.x, b2.y};
            #pragma unroll
            for (int i = 0; i < 3; ++i) {
                const int yo = r - i;
                if (yo >= 0 && yo < 4) {
                    #pragma unroll
                    for (int j = 0; j < 3; ++j) {
                        const float ww0 = w0[i * 3 + j];
                        const float ww1 = w1[i * 3 + j];
                        #pragma unroll
                        for (int q = 0; q < 4; ++q) {
                            acc0[yo][q] = fmaf(v[q + j], ww0, acc0[yo][q]);
                            acc1[yo][q] = fmaf(v[q + j], ww1, acc1[yo][q]);
                        }
                    }
                }
            }
        }
    }

    // ---- epilogue: bias + masked stores (R1 pattern, half-height per thread) ----
    const float bz0 = Bias[p];
    const float bz1 = Bias[p + 64];
    const int   xcol = x0 + cb;
    const int   yb   = y0 + (yh << 2);
    float* O0 = Out + (((size_t)b * OUTCH + p)      * OH) * OW;
    float* O1 = Out + (((size_t)b * OUTCH + p + 64) * OH) * OW;

    #pragma unroll
    for (int y = 0; y < 4; ++y) {
        const int oy = yb + y;
        if (oy < OH) {
            float* o0p = O0 + oy * OW + xcol;
            float* o1p = O1 + oy * OW + xcol;
            if (xcol + 3 < OW) {
                float4 s0, s1;
                s0.x = acc0[y][0] + bz0; s0.y = acc0[y][1] + bz0;
                s0.z = acc0[y][2] + bz0; s0.w = acc0[y][3] + bz0;
                s1.x = acc1[y][0] + bz1; s1.y = acc1[y][1] + bz1;
                s1.z = acc1[y][2] + bz1; s1.w = acc1[y][3] + bz1;
                *reinterpret_cast<float4*>(o0p) = s0;
                *reinterpret_cast<float4*>(o1p) = s1;
            } else {
                #pragma unroll
                for (int q = 0; q < 4; ++q) {
                    if (xcol + q < OW) {
                        o0p[q] = acc0[y][q] + bz0;
                        o1p[q] = acc1[y][q] + bz1;
                    }
                }
            }
        }
    }
}

extern "C" void kernel_launch(void* const* d_in, const int* in_sizes, int n_in,
                              void* d_out, int out_size, void* d_ws, size_t ws_size,
                              hipStream_t stream) {
    const float* X    = (const float*)d_in[0];
    const float* Wg   = (const float*)d_in[1];
    const float* Bias = (const float*)d_in[2];
    float*       Out  = (float*)d_out;

    float* Wp = nullptr;
    if (d_ws && ws_size >= 512 * 20 * sizeof(float)) {
        Wp = (float*)d_ws;
        prep_weights_kernel<<<36, 256, 0, stream>>>(Wg, Wp);
    }

    // round-1 grid order: tx fastest, then ty, then batch
    dim3 grid(8, 16, 16);   // 2048 blocks x 512 threads
    Group_Conv_84731114815961_kernel<<<grid, 512, 0, stream>>>(X, Wg, Bias, Wp, Out);
}

// Round 6
// 106.528 us; speedup vs baseline: 23.5493x; 2.2559x over previous
//
#include <hip/hip_runtime.h>

#define SUB   8
#define INCH  64
#define IMH   128
#define IMW   128
#define OUTCH 128
#define OH    126
#define OW    126

#define YT 8            // output rows per block
#define XT 16           // output cols per block
#define TR 10           // input rows staged (YT+2)
#define RS 20           // words per staged row (18 used + 2 pad)
#define NCH 39          // channels staged (32 owned + 7 halo)
#define CHS 204         // words per channel (10*20=200 + 4 pad)
#define LDS_WORDS (NCH * CHS)      // 7956 words = 31824 B -> 5 blocks/CU
#define LDS_VEC4  ((LDS_WORDS)/4)  // 1989
#define TRB 6           // input rows per y-half (4 out rows + 2)

// ---- weight prep: chunk c = s*64 + o0 (o0 in [0,64)): 20 floats, 16B aligned
//      t0..8  = W[o0][s][.][.],  t9..17 = W[o0+64][s][.][.]
__global__ __launch_bounds__(256)
void prep_weights_kernel(const float* __restrict__ Wg, float* __restrict__ Wp) {
    int idx = blockIdx.x * 256 + threadIdx.x;
    if (idx < 512 * 18) {
        int chunk = idx / 18;
        int t     = idx - chunk * 18;
        int s = chunk >> 6;
        int p = chunk & 63;
        int o  = (t < 9) ? p : p + 64;
        int tt = (t < 9) ? t : t - 9;
        Wp[chunk * 20 + t] = Wg[(o * SUB + s) * 9 + tt];
    }
}

// __launch_bounds__(256,3): w=3 -> VGPR cap ~84 (R1-proven). w>=4 spills the
// 32-acc working set to scratch and multiplies HBM traffic (R2/R4/R5 evidence).
__global__ __launch_bounds__(256, 3)
void Group_Conv_84731114815961_kernel(const float* __restrict__ X,
                                      const float* __restrict__ Wg,
                                      const float* __restrict__ Bias,
                                      const float* __restrict__ Wp,
                                      float* __restrict__ Out) {
    __shared__ float xin[LDS_WORDS];   // 31824 B -> 5 blocks/CU (LDS-limited)

    const int tx = blockIdx.x;        // 0..7
    const int ty = blockIdx.y;        // 0..15
    const int h  = blockIdx.z & 1;    // channel half
    const int b  = blockIdx.z >> 1;   // batch
    const int x0 = tx * XT;
    const int y0 = ty * YT;
    const int tid = threadIdx.x;

    // ---- stage NCH channels x 10 rows x 20 cols (VGPR float4 path) ----
    const float* Xb = X + (size_t)b * INCH * IMH * IMW;
    #pragma unroll
    for (int it = 0; it < 8; ++it) {
        int k = it * 256 + tid;
        if (k < LDS_VEC4) {
            int cl  = k / 51;                 // 51 float4 per channel (204 words)
            int rem = k - cl * 51;
            int r   = rem / 5;                // 0..10 (10 = pad slot)
            int col = (rem - r * 5) * 4;      // 0,4,8,12,16
            int cg  = (h * 32 + cl) & 63;
            int sr = y0 + r;   if (sr > IMH - 1) sr = IMH - 1;
            int sc = x0 + col; if (sc > IMW - 4) sc = IMW - 4;
            const float4 v = *reinterpret_cast<const float4*>(Xb + (cg * IMH + sr) * IMW + sc);
            *reinterpret_cast<float4*>(&xin[k * 4]) = v;
        }
    }
    __syncthreads();

    const int p  = tid >> 3;          // 0..31  o-pair within half
    const int yh = (tid >> 2) & 1;    // y half (rows 4yh..4yh+3)
    const int xg = tid & 3;           // 4-col group
    const int cb = xg << 2;
    const int o0 = h * 32 + p;        // o1 = o0 + 64

    float acc0[4][4];
    float acc1[4][4];
    #pragma unroll
    for (int y = 0; y < 4; ++y)
        #pragma unroll
        for (int q = 0; q < 4; ++q) { acc0[y][q] = 0.f; acc1[y][q] = 0.f; }

    const bool useWp = (Wp != nullptr);

    for (int s = 0; s < SUB; ++s) {
        const int cl = p + s;         // 0..38 staged channel index
        float w0[9], w1[9];
        if (useWp) {
            const float4* wc = reinterpret_cast<const float4*>(Wp + ((s << 6) + o0) * 20);
            const float4 f0 = wc[0], f1 = wc[1], f2 = wc[2], f3 = wc[3], f4 = wc[4];
            w0[0]=f0.x; w0[1]=f0.y; w0[2]=f0.z; w0[3]=f0.w;
            w0[4]=f1.x; w0[5]=f1.y; w0[6]=f1.z; w0[7]=f1.w;
            w0[8]=f2.x;
            w1[0]=f2.y; w1[1]=f2.z; w1[2]=f2.w;
            w1[3]=f3.x; w1[4]=f3.y; w1[5]=f3.z; w1[6]=f3.w;
            w1[7]=f4.x; w1[8]=f4.y;
        } else {
            const float* w0p = Wg + (o0 * SUB + s) * 9;
            const float* w1p = Wg + ((o0 + 64) * SUB + s) * 9;
            #pragma unroll
            for (int t = 0; t < 9; ++t) { w0[t] = w0p[t]; w1[t] = w1p[t]; }
        }

        const float* base = &xin[cl * CHS + (yh << 2) * RS + cb];
        #pragma unroll
        for (int r = 0; r < TRB; ++r) {
            const float4 a  = *reinterpret_cast<const float4*>(base + r * RS);
            const float2 b2 = *reinterpret_cast<const float2*>(base + r * RS + 4);
            float v[6];
            v[0] = a.x; v[1] = a.y; v[2] = a.z; v[3] = a.w; v[4] = b2.x; v[5] = b2.y;
            #pragma unroll
            for (int i = 0; i < 3; ++i) {
                const int yo = r - i;
                if (yo >= 0 && yo < 4) {
                    #pragma unroll
                    for (int j = 0; j < 3; ++j) {
                        const float ww0 = w0[i * 3 + j];
                        const float ww1 = w1[i * 3 + j];
                        #pragma unroll
                        for (int q = 0; q < 4; ++q) {
                            acc0[yo][q] = fmaf(v[q + j], ww0, acc0[yo][q]);
                            acc1[yo][q] = fmaf(v[q + j], ww1, acc1[yo][q]);
                        }
                    }
                }
            }
        }
    }

    // ---- epilogue: bias + masked stores ----
    const float bz0 = Bias[o0];
    const float bz1 = Bias[o0 + 64];
    const int   xcol = x0 + cb;
    const int   yb   = y0 + (yh << 2);
    float* O0 = Out + (((size_t)b * OUTCH + o0)      * OH) * OW;
    float* O1 = Out + (((size_t)b * OUTCH + o0 + 64) * OH) * OW;

    #pragma unroll
    for (int y = 0; y < 4; ++y) {
        const int oy = yb + y;
        if (oy < OH) {
            float* o0p = O0 + oy * OW + xcol;
            float* o1p = O1 + oy * OW + xcol;
            if (xcol + 3 < OW) {
                float4 s0, s1;
                s0.x = acc0[y][0] + bz0; s0.y = acc0[y][1] + bz0;
                s0.z = acc0[y][2] + bz0; s0.w = acc0[y][3] + bz0;
                s1.x = acc1[y][0] + bz1; s1.y = acc1[y][1] + bz1;
                s1.z = acc1[y][2] + bz1; s1.w = acc1[y][3] + bz1;
                *reinterpret_cast<float4*>(o0p) = s0;
                *reinterpret_cast<float4*>(o1p) = s1;
            } else {
                #pragma unroll
                for (int q = 0; q < 4; ++q) {
                    if (xcol + q < OW) {
                        o0p[q] = acc0[y][q] + bz0;
                        o1p[q] = acc1[y][q] + bz1;
                    }
                }
            }
        }
    }
}

extern "C" void kernel_launch(void* const* d_in, const int* in_sizes, int n_in,
                              void* d_out, int out_size, void* d_ws, size_t ws_size,
                              hipStream_t stream) {
    const float* X    = (const float*)d_in[0];
    const float* Wg   = (const float*)d_in[1];
    const float* Bias = (const float*)d_in[2];
    float*       Out  = (float*)d_out;

    float* Wp = nullptr;
    if (d_ws && ws_size >= 512 * 20 * sizeof(float)) {
        Wp = (float*)d_ws;
        prep_weights_kernel<<<36, 256, 0, stream>>>(Wg, Wp);
    }

    dim3 grid(8, 16, 32);   // x-tiles, y-tiles, (batch x channel-half)
    Group_Conv_84731114815961_kernel<<<grid, 256, 0, stream>>>(X, Wg, Bias, Wp, Out);
}